// Round 5
// baseline (565.031 us; speedup 1.0000x reference)
//
#include <hip/hip_runtime.h>

#define HW 4096
#define CAP 262144u

typedef short bf16x8 __attribute__((ext_vector_type(8)));
typedef float f32x16 __attribute__((ext_vector_type(16)));

__device__ __forceinline__ ushort f2bf_rne(float f) {
    unsigned u = __float_as_uint(f);
    return (ushort)((u + 0x7FFFu + ((u >> 16) & 1u)) >> 16);
}

// ---------------------------------------------------------------------------
// init: zero candidate counter + per-(b,n) best keys.
// ---------------------------------------------------------------------------
__global__ __launch_bounds__(256) void init_kernel(
    unsigned long long* __restrict__ best, unsigned* __restrict__ cnt)
{
    int i = blockIdx.x * 256 + threadIdx.x;   // 16384
    best[i] = 0ull;
    if (i == 0) cnt[0] = 0u;
}

// ---------------------------------------------------------------------------
// Kernel 1: 1x1-conv projection.
// Outputs: Qt/Pt fp32 [b][n][128] (rescore), qnorm, and bf16 packs in
// 32x32x16-MFMA fragment order:
//   PK[b][t32][ks][lane][j] = X[c = ks*16 + (lane>>5)*8 + j][n = t32*32 + (lane&31)]
// (identical layout for A(Q) and B(P) operands).
// ---------------------------------------------------------------------------
__global__ __launch_bounds__(256) void proj_kernel(
    const float* __restrict__ Fq, const float* __restrict__ Fp,
    const float* __restrict__ Wm, const float* __restrict__ bias,
    float* __restrict__ Qt, float* __restrict__ Pt,
    ushort* __restrict__ Qpk, ushort* __restrict__ Ppk,
    float* __restrict__ qnorm)
{
    __shared__ float Xs[64][64];
    __shared__ float sq[4][64];

    const int tid = threadIdx.x;
    const int z = blockIdx.z;
    const float* __restrict__ X = z ? Fp : Fq;
    const int b  = blockIdx.y;
    const int n0 = blockIdx.x * 64;
    const int n  = tid & 63;
    const int og = __builtin_amdgcn_readfirstlane(tid >> 6);

    float acc[32];
    #pragma unroll
    for (int j = 0; j < 32; ++j) acc[j] = 0.f;

    for (int cc = 0; cc < 4; ++cc) {
        #pragma unroll
        for (int i = 0; i < 16; ++i) {
            int idx = tid + i * 256;
            int r = idx >> 6, nn = idx & 63;
            Xs[r][nn] = X[(size_t)(b * 256 + cc * 64 + r) * HW + n0 + nn];
        }
        __syncthreads();
        for (int r = 0; r < 64; ++r) {
            float x = Xs[r][n];
            int c = cc * 64 + r;
            #pragma unroll
            for (int j = 0; j < 32; ++j)
                acc[j] += Wm[(og * 32 + j) * 256 + c] * x;   // scalar W loads
        }
        __syncthreads();
    }

    #pragma unroll
    for (int j = 0; j < 32; ++j) acc[j] += bias[og * 32 + j];

    float ssq = 0.f;
    #pragma unroll
    for (int j = 0; j < 32; ++j) ssq += acc[j] * acc[j];
    sq[og][n] = ssq;
    __syncthreads();
    float tot = sq[0][n] + sq[1][n] + sq[2][n] + sq[3][n];
    if (z) {
        float s = 1.0f / sqrtf(tot);
        #pragma unroll
        for (int j = 0; j < 32; ++j) acc[j] *= s;
    } else if (og == 0) {
        qnorm[b * HW + n0 + n] = sqrtf(tot);
    }

    // fp32 transposed output for rescore
    {
        float* __restrict__ T = z ? Pt : Qt;
        size_t tb = ((size_t)b * HW + n0 + n) * 128 + og * 32;
        #pragma unroll
        for (int j = 0; j < 32; j += 4)
            *(float4*)&T[tb + j] = make_float4(acc[j], acc[j+1], acc[j+2], acc[j+3]);
    }
    // bf16 pack, 32x32x16 fragment order.  This thread owns channels
    // c = og*32 + [0,32) of pixel na: group g of 8 consecutive channels ->
    // ks = og*2 + (g>>1), k-half = g&1, j = c&7  (one 16B store each).
    {
        ushort* __restrict__ PK = z ? Ppk : Qpk;
        const int na  = n0 + n;
        const int t32 = na >> 5;
        const int nl  = na & 31;
        #pragma unroll
        for (int g = 0; g < 4; ++g) {
            const int ks = og * 2 + (g >> 1);
            const int lt = nl + 32 * (g & 1);
            ushort u[8];
            #pragma unroll
            for (int k = 0; k < 8; ++k) u[k] = f2bf_rne(acc[g * 8 + k]);
            size_t pk = ((((size_t)b * 128 + t32) * 8 + ks) * 64 + lt) * 8;
            uint4 w;
            w.x = (unsigned)u[0] | ((unsigned)u[1] << 16);
            w.y = (unsigned)u[2] | ((unsigned)u[3] << 16);
            w.z = (unsigned)u[4] | ((unsigned)u[5] << 16);
            w.w = (unsigned)u[6] | ((unsigned)u[7] << 16);
            *(uint4*)&PK[pk] = w;
        }
    }
}

// ---------------------------------------------------------------------------
// MFMA sim, shared body.  Grid (32,4,4): block = 128 n x 1024 m.
// Wave w owns one 32-row n-tile; per 128-m chunk: 4 m-tiles, each one
// 32x32x16 MFMA chained 8 deep over K=128.  NO persistent operand arrays:
// every A/B fragment is ds_read immediately before its MFMA (nothing to
// spill; worst-case remat re-reads LDS).  acc: 16 VGPRs.
// D mapping (HW-verified): col m = lane&31, row = (reg&3)+8*(reg>>2)+4*(lane>>5).
// PASS 1 -> per-(n, ms) max; PASS 2 -> emit m with s >= thr[n].
// Identical MFMA chain order in both passes -> bitwise-identical s.
// ---------------------------------------------------------------------------
template<int PASS>
__device__ __forceinline__ void sim_body(
    const ushort* __restrict__ Qpk, const ushort* __restrict__ Ppk,
    const float* __restrict__ thr, float* __restrict__ Vmax,
    unsigned* __restrict__ cnt, unsigned* __restrict__ cand)
{
    __shared__ ushort Qs[16384];   // 32 KB: 4 n-tiles x 8 ks x 64 lanes x 8
    __shared__ ushort Bs[16384];   // 32 KB: 4 m-tiles x 8 ks x 64 lanes x 8

    const int tid  = threadIdx.x;
    const int lane = tid & 63;
    const int w    = tid >> 6;
    const int nb   = blockIdx.x;   // 32
    const int b    = blockIdx.y;   // 4
    const int ms   = blockIdx.z;   // 4 -> m in [ms*1024, ms*1024+1024)

    // stage Q tile (pack order == LDS order, lane-linear)
    {
        const uint4* src = (const uint4*)(Qpk + ((size_t)b * 128 + nb * 4) * 4096);
        uint4* dst = (uint4*)Qs;
        #pragma unroll
        for (int it = 0; it < 8; ++it) dst[it * 256 + tid] = src[it * 256 + tid];
    }

    float bestv[16];
    float thrreg[16];
    if (PASS == 1) {
        #pragma unroll
        for (int r = 0; r < 16; ++r) bestv[r] = -1e30f;
    } else {
        #pragma unroll
        for (int r = 0; r < 16; ++r) {
            int nl_ = (r & 3) + 8 * (r >> 2) + 4 * (lane >> 5);
            thrreg[r] = thr[b * HW + nb * 128 + w * 32 + nl_];
        }
    }

    for (int ch = 0; ch < 8; ++ch) {
        __syncthreads();   // prior chunk's Bs reads done (also orders Qs stage)
        {
            const uint4* src = (const uint4*)(Ppk +
                ((size_t)b * 128 + ms * 32 + ch * 4) * 4096);
            uint4* dst = (uint4*)Bs;
            #pragma unroll
            for (int it = 0; it < 8; ++it) dst[it * 256 + tid] = src[it * 256 + tid];
        }
        __syncthreads();

        for (int mtl = 0; mtl < 4; ++mtl) {
            f32x16 acc;
            #pragma unroll
            for (int r = 0; r < 16; ++r) acc[r] = 0.f;

            #pragma unroll
            for (int ks = 0; ks < 8; ++ks) {
                bf16x8 a  = *(const bf16x8*)&Qs[((w   * 8 + ks) * 64 + lane) * 8];
                bf16x8 bb = *(const bf16x8*)&Bs[((mtl * 8 + ks) * 64 + lane) * 8];
                acc = __builtin_amdgcn_mfma_f32_32x32x16_bf16(a, bb, acc, 0, 0, 0);
            }

            if (PASS == 1) {
                #pragma unroll
                for (int r = 0; r < 16; ++r)
                    bestv[r] = fmaxf(bestv[r], acc[r]);
            } else {
                const int m = ms * 1024 + ch * 128 + mtl * 32 + (lane & 31);
                #pragma unroll
                for (int r = 0; r < 16; ++r) {
                    if (acc[r] >= thrreg[r]) {
                        int nl_ = (r & 3) + 8 * (r >> 2) + 4 * (lane >> 5);
                        int na = nb * 128 + w * 32 + nl_;
                        unsigned idx = atomicAdd(cnt, 1u);
                        if (idx < CAP)
                            cand[idx] = ((unsigned)b << 24) | ((unsigned)na << 12) | (unsigned)m;
                    }
                }
            }
        }
    }

    if (PASS == 1) {
        // reduce over the 32 column-lanes (bits 0..4 of lane)
        #pragma unroll
        for (int r = 0; r < 16; ++r) {
            float v = bestv[r];
            #pragma unroll
            for (int d = 1; d < 32; d <<= 1)
                v = fmaxf(v, __shfl_xor(v, d, 64));
            if ((lane & 31) == 0) {
                int nl_ = (r & 3) + 8 * (r >> 2) + 4 * (lane >> 5);
                int na = nb * 128 + w * 32 + nl_;
                Vmax[((size_t)b * HW + na) * 4 + ms] = v;
            }
        }
    }
}

__global__ __launch_bounds__(256, 2) void sim_max_kernel(
    const ushort* __restrict__ Qpk, const ushort* __restrict__ Ppk,
    float* __restrict__ Vmax)
{
    sim_body<1>(Qpk, Ppk, nullptr, Vmax, nullptr, nullptr);
}

__global__ __launch_bounds__(256, 2) void sim_emit_kernel(
    const ushort* __restrict__ Qpk, const ushort* __restrict__ Ppk,
    const float* __restrict__ thr,
    unsigned* __restrict__ cnt, unsigned* __restrict__ cand)
{
    sim_body<2>(Qpk, Ppk, thr, nullptr, cnt, cand);
}

// ---------------------------------------------------------------------------
// threshold: thr[n] = max_s Vmax[n][s] - (0.016*||q_n|| + 1e-6)
// margin: |s_bf16 - s_fp32| < 0.00787*||q||  ->  2*delta < 0.016*||q||
// ---------------------------------------------------------------------------
__global__ __launch_bounds__(256) void thresh_kernel(
    const float* __restrict__ Vmax, const float* __restrict__ qnorm,
    float* __restrict__ thr)
{
    int i = blockIdx.x * 256 + threadIdx.x;   // 16384
    float g = -1e30f;
    #pragma unroll
    for (int s = 0; s < 4; ++s) g = fmaxf(g, Vmax[(size_t)i * 4 + s]);
    thr[i] = g - (0.016f * qnorm[i] + 1e-6f);
}

// ---------------------------------------------------------------------------
// exact fp32 rescore (sequential-c fma chain, the order that matched np in
// rounds 1-4).  Merge via packed u64 atomicMax: (orderedbits(v)<<32)|(4095-m).
// ---------------------------------------------------------------------------
__global__ __launch_bounds__(256) void rescore_kernel(
    const float* __restrict__ Qt, const float* __restrict__ Pt,
    const unsigned* __restrict__ cand, const unsigned* __restrict__ cnt,
    unsigned long long* __restrict__ best)
{
    unsigned total = cnt[0];
    if (total > CAP) total = CAP;
    for (unsigned i = blockIdx.x * 256 + threadIdx.x; i < total; i += gridDim.x * 256) {
        unsigned c = cand[i];
        int m = c & 0xFFF, n = (c >> 12) & 0xFFF, b = c >> 24;
        const float* __restrict__ q = Qt + ((size_t)b * HW + n) * 128;
        const float* __restrict__ p = Pt + ((size_t)b * HW + m) * 128;
        float acc = 0.f;
        for (int k = 0; k < 128; ++k) acc += q[k] * p[k];
        unsigned u = __float_as_uint(acc);
        unsigned kk = (u & 0x80000000u) ? ~u : (u | 0x80000000u);
        unsigned long long key = ((unsigned long long)kk << 32) | (unsigned)(4095 - m);
        atomicMax(&best[(size_t)b * HW + n], key);
    }
}

// ---------------------------------------------------------------------------
// gather: out[b][c][n] = Fp[b][c][m(n)]; stage each 16 KB Fp row in LDS.
// ---------------------------------------------------------------------------
__global__ __launch_bounds__(256) void gather_kernel(
    const float* __restrict__ Fp, const unsigned long long* __restrict__ best,
    float* __restrict__ out)
{
    __shared__ float row[4096];
    const int blk = blockIdx.x;      // 1024 = 4b x 256c
    const int c = blk & 255;
    const int b = blk >> 8;
    const int tid = threadIdx.x;

    const float* __restrict__ src = Fp + ((size_t)b * 256 + c) * HW;
    #pragma unroll
    for (int it = 0; it < 4; ++it) {
        int f = it * 256 + tid;
        *(float4*)&row[f * 4] = *(const float4*)&src[f * 4];
    }
    __syncthreads();

    float* __restrict__ dst = out + ((size_t)b * 256 + c) * HW;
    #pragma unroll
    for (int it = 0; it < 16; ++it) {
        int n = it * 256 + tid;
        int m = 4095 - (int)(best[(size_t)b * HW + n] & 0xFFFull);
        dst[n] = row[m];
    }
}

extern "C" void kernel_launch(void* const* d_in, const int* in_sizes, int n_in,
                              void* d_out, int out_size, void* d_ws, size_t ws_size,
                              hipStream_t stream) {
    const float* Fq   = (const float*)d_in[0];
    const float* Fp   = (const float*)d_in[1];
    const float* Wm   = (const float*)d_in[2];
    const float* bias = (const float*)d_in[3];
    float* out = (float*)d_out;

    char* base = (char*)d_ws;
    float*  Qt    = (float*)(base);                               // 8 MB
    float*  Pt    = (float*)(base + (8u << 20));                  // 8 MB
    ushort* Qpk   = (ushort*)(base + (16u << 20));                // 4 MB
    ushort* Ppk   = (ushort*)(base + (20u << 20));                // 4 MB
    char* x = base + (24u << 20);
    float*  qnorm = (float*)x;              x += 65536;           // 64 KB
    float*  Vmax  = (float*)x;              x += 262144;          // 256 KB
    float*  thr   = (float*)x;              x += 65536;           // 64 KB
    unsigned long long* best = (unsigned long long*)x; x += 131072; // 128 KB
    unsigned* cnt  = (unsigned*)x;          x += 16;
    unsigned* cand = (unsigned*)x;                                 // 1 MB

    init_kernel<<<64, 256, 0, stream>>>(best, cnt);
    proj_kernel<<<dim3(64, 4, 2), 256, 0, stream>>>(Fq, Fp, Wm, bias,
                                                    Qt, Pt, Qpk, Ppk, qnorm);
    sim_max_kernel<<<dim3(32, 4, 4), 256, 0, stream>>>(Qpk, Ppk, Vmax);
    thresh_kernel<<<64, 256, 0, stream>>>(Vmax, qnorm, thr);
    sim_emit_kernel<<<dim3(32, 4, 4), 256, 0, stream>>>(Qpk, Ppk, thr, cnt, cand);
    rescore_kernel<<<128, 256, 0, stream>>>(Qt, Pt, cand, cnt, best);
    gather_kernel<<<1024, 256, 0, stream>>>(Fp, best, out);
}

// Round 6
// 243.379 us; speedup vs baseline: 2.3216x; 2.3216x over previous
//
#include <hip/hip_runtime.h>

#define HW 4096
#define BCAP 1024u     // per-block candidate slots (expected ~64/block)
#define OCAP 65536u    // global overflow list (expected 0 used)

typedef short bf16x8 __attribute__((ext_vector_type(8)));
typedef float f32x16 __attribute__((ext_vector_type(16)));

__device__ __forceinline__ ushort f2bf_rne(float f) {
    unsigned u = __float_as_uint(f);
    return (ushort)((u + 0x7FFFu + ((u >> 16) & 1u)) >> 16);
}

// ---------------------------------------------------------------------------
// init: zero per-(b,n) best keys, per-block candidate counts, overflow count.
// ---------------------------------------------------------------------------
__global__ __launch_bounds__(256) void init_kernel(
    unsigned long long* __restrict__ best, unsigned* __restrict__ bcnt,
    unsigned* __restrict__ ocnt)
{
    int i = blockIdx.x * 256 + threadIdx.x;   // 16384
    best[i] = 0ull;
    if (i < 512) bcnt[i] = 0u;
    if (i == 0) ocnt[0] = 0u;
}

// ---------------------------------------------------------------------------
// Kernel 1: 1x1-conv projection (unchanged; validated by R5 absmax=0).
// Outputs: Qt/Pt fp32 [b][n][128] (rescore), qnorm, and bf16 packs in
// 32x32x16-MFMA fragment order:
//   PK[b][t32][ks][lane][j] = X[c = ks*16 + (lane>>5)*8 + j][n = t32*32 + (lane&31)]
// ---------------------------------------------------------------------------
__global__ __launch_bounds__(256) void proj_kernel(
    const float* __restrict__ Fq, const float* __restrict__ Fp,
    const float* __restrict__ Wm, const float* __restrict__ bias,
    float* __restrict__ Qt, float* __restrict__ Pt,
    ushort* __restrict__ Qpk, ushort* __restrict__ Ppk,
    float* __restrict__ qnorm)
{
    __shared__ float Xs[64][64];
    __shared__ float sq[4][64];

    const int tid = threadIdx.x;
    const int z = blockIdx.z;
    const float* __restrict__ X = z ? Fp : Fq;
    const int b  = blockIdx.y;
    const int n0 = blockIdx.x * 64;
    const int n  = tid & 63;
    const int og = __builtin_amdgcn_readfirstlane(tid >> 6);

    float acc[32];
    #pragma unroll
    for (int j = 0; j < 32; ++j) acc[j] = 0.f;

    for (int cc = 0; cc < 4; ++cc) {
        #pragma unroll
        for (int i = 0; i < 16; ++i) {
            int idx = tid + i * 256;
            int r = idx >> 6, nn = idx & 63;
            Xs[r][nn] = X[(size_t)(b * 256 + cc * 64 + r) * HW + n0 + nn];
        }
        __syncthreads();
        for (int r = 0; r < 64; ++r) {
            float x = Xs[r][n];
            int c = cc * 64 + r;
            #pragma unroll
            for (int j = 0; j < 32; ++j)
                acc[j] += Wm[(og * 32 + j) * 256 + c] * x;   // scalar W loads
        }
        __syncthreads();
    }

    #pragma unroll
    for (int j = 0; j < 32; ++j) acc[j] += bias[og * 32 + j];

    float ssq = 0.f;
    #pragma unroll
    for (int j = 0; j < 32; ++j) ssq += acc[j] * acc[j];
    sq[og][n] = ssq;
    __syncthreads();
    float tot = sq[0][n] + sq[1][n] + sq[2][n] + sq[3][n];
    if (z) {
        float s = 1.0f / sqrtf(tot);
        #pragma unroll
        for (int j = 0; j < 32; ++j) acc[j] *= s;
    } else if (og == 0) {
        qnorm[b * HW + n0 + n] = sqrtf(tot);
    }

    {
        float* __restrict__ T = z ? Pt : Qt;
        size_t tb = ((size_t)b * HW + n0 + n) * 128 + og * 32;
        #pragma unroll
        for (int j = 0; j < 32; j += 4)
            *(float4*)&T[tb + j] = make_float4(acc[j], acc[j+1], acc[j+2], acc[j+3]);
    }
    {
        ushort* __restrict__ PK = z ? Ppk : Qpk;
        const int na  = n0 + n;
        const int t32 = na >> 5;
        const int nl  = na & 31;
        #pragma unroll
        for (int g = 0; g < 4; ++g) {
            const int ks = og * 2 + (g >> 1);
            const int lt = nl + 32 * (g & 1);
            ushort u[8];
            #pragma unroll
            for (int k = 0; k < 8; ++k) u[k] = f2bf_rne(acc[g * 8 + k]);
            size_t pk = ((((size_t)b * 128 + t32) * 8 + ks) * 64 + lt) * 8;
            uint4 w;
            w.x = (unsigned)u[0] | ((unsigned)u[1] << 16);
            w.y = (unsigned)u[2] | ((unsigned)u[3] << 16);
            w.z = (unsigned)u[4] | ((unsigned)u[5] << 16);
            w.w = (unsigned)u[6] | ((unsigned)u[7] << 16);
            *(uint4*)&PK[pk] = w;
        }
    }
}

// ---------------------------------------------------------------------------
// PASS 1: MFMA sim max.  Grid (32,4,4): block = 128 n x 1024 m; wave owns a
// 32-row n-tile; 8 m-chunks of 128 through 32 KB LDS; 32x32x16 MFMA chained
// 8 deep over K=128.  D mapping: m = lane&31, n = (r&3)+8*(r>>2)+4*(lane>>5).
// ---------------------------------------------------------------------------
__global__ __launch_bounds__(256, 2) void sim_max_kernel(
    const ushort* __restrict__ Qpk, const ushort* __restrict__ Ppk,
    float* __restrict__ Vmax)
{
    __shared__ ushort Qs[16384];
    __shared__ ushort Bs[16384];

    const int tid  = threadIdx.x;
    const int lane = tid & 63;
    const int w    = tid >> 6;
    const int nb   = blockIdx.x;
    const int b    = blockIdx.y;
    const int ms   = blockIdx.z;

    {
        const uint4* src = (const uint4*)(Qpk + ((size_t)b * 128 + nb * 4) * 4096);
        uint4* dst = (uint4*)Qs;
        #pragma unroll
        for (int it = 0; it < 8; ++it) dst[it * 256 + tid] = src[it * 256 + tid];
    }

    float bestv[16];
    #pragma unroll
    for (int r = 0; r < 16; ++r) bestv[r] = -1e30f;

    for (int ch = 0; ch < 8; ++ch) {
        __syncthreads();
        {
            const uint4* src = (const uint4*)(Ppk +
                ((size_t)b * 128 + ms * 32 + ch * 4) * 4096);
            uint4* dst = (uint4*)Bs;
            #pragma unroll
            for (int it = 0; it < 8; ++it) dst[it * 256 + tid] = src[it * 256 + tid];
        }
        __syncthreads();

        for (int mtl = 0; mtl < 4; ++mtl) {
            f32x16 acc;
            #pragma unroll
            for (int r = 0; r < 16; ++r) acc[r] = 0.f;
            #pragma unroll
            for (int ks = 0; ks < 8; ++ks) {
                bf16x8 a  = *(const bf16x8*)&Qs[((w   * 8 + ks) * 64 + lane) * 8];
                bf16x8 bb = *(const bf16x8*)&Bs[((mtl * 8 + ks) * 64 + lane) * 8];
                acc = __builtin_amdgcn_mfma_f32_32x32x16_bf16(a, bb, acc, 0, 0, 0);
            }
            #pragma unroll
            for (int r = 0; r < 16; ++r)
                bestv[r] = fmaxf(bestv[r], acc[r]);
        }
    }

    #pragma unroll
    for (int r = 0; r < 16; ++r) {
        float v = bestv[r];
        #pragma unroll
        for (int d = 1; d < 32; d <<= 1)
            v = fmaxf(v, __shfl_xor(v, d, 64));
        if ((lane & 31) == 0) {
            int nl_ = (r & 3) + 8 * (r >> 2) + 4 * (lane >> 5);
            int na = nb * 128 + w * 32 + nl_;
            Vmax[((size_t)b * HW + na) * 4 + ms] = v;
        }
    }
}

// ---------------------------------------------------------------------------
// PASS 2: emit candidates with s >= thr[n].  SAME MFMA chain order as pass 1
// -> bitwise-identical s.  R5 forensics: a single global return-value
// atomicAdd counter serialized ~32k device-scope RMWs at ~10 ns each = the
// entire 343 us.  Now: LDS counter + per-block candidate region; the global
// path survives only as an overflow fallback (expected 0 uses).
// ---------------------------------------------------------------------------
__global__ __launch_bounds__(256, 2) void sim_emit_kernel(
    const ushort* __restrict__ Qpk, const ushort* __restrict__ Ppk,
    const float* __restrict__ thr,
    unsigned* __restrict__ cand, unsigned* __restrict__ bcnt,
    unsigned* __restrict__ ocand, unsigned* __restrict__ ocnt)
{
    __shared__ ushort Qs[16384];
    __shared__ ushort Bs[16384];
    __shared__ unsigned lds_cand[BCAP];
    __shared__ unsigned lds_cnt;

    const int tid  = threadIdx.x;
    const int lane = tid & 63;
    const int w    = tid >> 6;
    const int nb   = blockIdx.x;
    const int b    = blockIdx.y;
    const int ms   = blockIdx.z;
    const int blk  = nb + 32 * (b + 4 * ms);   // 512 regions

    if (tid == 0) lds_cnt = 0u;

    {
        const uint4* src = (const uint4*)(Qpk + ((size_t)b * 128 + nb * 4) * 4096);
        uint4* dst = (uint4*)Qs;
        #pragma unroll
        for (int it = 0; it < 8; ++it) dst[it * 256 + tid] = src[it * 256 + tid];
    }

    float thrreg[16];
    #pragma unroll
    for (int r = 0; r < 16; ++r) {
        int nl_ = (r & 3) + 8 * (r >> 2) + 4 * (lane >> 5);
        thrreg[r] = thr[b * HW + nb * 128 + w * 32 + nl_];
    }

    for (int ch = 0; ch < 8; ++ch) {
        __syncthreads();   // orders lds_cnt init + Qs stage + prior Bs reads
        {
            const uint4* src = (const uint4*)(Ppk +
                ((size_t)b * 128 + ms * 32 + ch * 4) * 4096);
            uint4* dst = (uint4*)Bs;
            #pragma unroll
            for (int it = 0; it < 8; ++it) dst[it * 256 + tid] = src[it * 256 + tid];
        }
        __syncthreads();

        for (int mtl = 0; mtl < 4; ++mtl) {
            f32x16 acc;
            #pragma unroll
            for (int r = 0; r < 16; ++r) acc[r] = 0.f;
            #pragma unroll
            for (int ks = 0; ks < 8; ++ks) {
                bf16x8 a  = *(const bf16x8*)&Qs[((w   * 8 + ks) * 64 + lane) * 8];
                bf16x8 bb = *(const bf16x8*)&Bs[((mtl * 8 + ks) * 64 + lane) * 8];
                acc = __builtin_amdgcn_mfma_f32_32x32x16_bf16(a, bb, acc, 0, 0, 0);
            }

            const int m = ms * 1024 + ch * 128 + mtl * 32 + (lane & 31);
            #pragma unroll
            for (int r = 0; r < 16; ++r) {
                if (acc[r] >= thrreg[r]) {
                    int nl_ = (r & 3) + 8 * (r >> 2) + 4 * (lane >> 5);
                    int na = nb * 128 + w * 32 + nl_;
                    unsigned enc = ((unsigned)b << 24) | ((unsigned)na << 12) | (unsigned)m;
                    unsigned pos = atomicAdd(&lds_cnt, 1u);   // LDS: per-CU, fast
                    if (pos < BCAP) {
                        lds_cand[pos] = enc;
                    } else {                                  // overflow fallback
                        unsigned op = atomicAdd(ocnt, 1u);
                        if (op < OCAP) ocand[op] = enc;
                    }
                }
            }
        }
    }

    __syncthreads();
    unsigned cnt = lds_cnt;
    if (cnt > BCAP) cnt = BCAP;
    for (unsigned i = tid; i < cnt; i += 256)
        cand[(size_t)blk * BCAP + i] = lds_cand[i];
    if (tid == 0) bcnt[blk] = cnt;
}

// ---------------------------------------------------------------------------
// threshold: thr[n] = max_s Vmax[n][s] - (0.016*||q_n|| + 1e-6)
// margin: |s_bf16 - s_fp32| < 0.00787*||q||  ->  2*delta < 0.016*||q||
// ---------------------------------------------------------------------------
__global__ __launch_bounds__(256) void thresh_kernel(
    const float* __restrict__ Vmax, const float* __restrict__ qnorm,
    float* __restrict__ thr)
{
    int i = blockIdx.x * 256 + threadIdx.x;   // 16384
    float g = -1e30f;
    #pragma unroll
    for (int s = 0; s < 4; ++s) g = fmaxf(g, Vmax[(size_t)i * 4 + s]);
    thr[i] = g - (0.016f * qnorm[i] + 1e-6f);
}

// ---------------------------------------------------------------------------
// exact fp32 rescore (sequential-c fma chain, the order that matched np in
// rounds 1-5).  Block j consumes region j, then grid-strides the overflow
// list.  Merge via packed u64 atomicMax (distinct addresses, ~2 ops each).
// ---------------------------------------------------------------------------
__device__ __forceinline__ void rescore_one(
    const float* __restrict__ Qt, const float* __restrict__ Pt,
    unsigned c, unsigned long long* __restrict__ best)
{
    int m = c & 0xFFF, n = (c >> 12) & 0xFFF, b = c >> 24;
    const float* __restrict__ q = Qt + ((size_t)b * HW + n) * 128;
    const float* __restrict__ p = Pt + ((size_t)b * HW + m) * 128;
    float acc = 0.f;
    for (int k = 0; k < 128; ++k) acc += q[k] * p[k];
    unsigned u = __float_as_uint(acc);
    unsigned kk = (u & 0x80000000u) ? ~u : (u | 0x80000000u);
    unsigned long long key = ((unsigned long long)kk << 32) | (unsigned)(4095 - m);
    atomicMax(&best[(size_t)b * HW + n], key);
}

__global__ __launch_bounds__(256) void rescore_kernel(
    const float* __restrict__ Qt, const float* __restrict__ Pt,
    const unsigned* __restrict__ cand, const unsigned* __restrict__ bcnt,
    const unsigned* __restrict__ ocand, const unsigned* __restrict__ ocnt,
    unsigned long long* __restrict__ best)
{
    const int blk = blockIdx.x;          // 512
    const int tid = threadIdx.x;
    unsigned cnt = bcnt[blk];
    for (unsigned i = tid; i < cnt; i += 256)
        rescore_one(Qt, Pt, cand[(size_t)blk * BCAP + i], best);

    unsigned total = ocnt[0];
    if (total > OCAP) total = OCAP;
    for (unsigned i = blk * 256 + tid; i < total; i += 512 * 256)
        rescore_one(Qt, Pt, ocand[i], best);
}

// ---------------------------------------------------------------------------
// gather: out[b][c][n] = Fp[b][c][m(n)]; stage each 16 KB Fp row in LDS.
// ---------------------------------------------------------------------------
__global__ __launch_bounds__(256) void gather_kernel(
    const float* __restrict__ Fp, const unsigned long long* __restrict__ best,
    float* __restrict__ out)
{
    __shared__ float row[4096];
    const int blk = blockIdx.x;      // 1024 = 4b x 256c
    const int c = blk & 255;
    const int b = blk >> 8;
    const int tid = threadIdx.x;

    const float* __restrict__ src = Fp + ((size_t)b * 256 + c) * HW;
    #pragma unroll
    for (int it = 0; it < 4; ++it) {
        int f = it * 256 + tid;
        *(float4*)&row[f * 4] = *(const float4*)&src[f * 4];
    }
    __syncthreads();

    float* __restrict__ dst = out + ((size_t)b * 256 + c) * HW;
    #pragma unroll
    for (int it = 0; it < 16; ++it) {
        int n = it * 256 + tid;
        int m = 4095 - (int)(best[(size_t)b * HW + n] & 0xFFFull);
        dst[n] = row[m];
    }
}

extern "C" void kernel_launch(void* const* d_in, const int* in_sizes, int n_in,
                              void* d_out, int out_size, void* d_ws, size_t ws_size,
                              hipStream_t stream) {
    const float* Fq   = (const float*)d_in[0];
    const float* Fp   = (const float*)d_in[1];
    const float* Wm   = (const float*)d_in[2];
    const float* bias = (const float*)d_in[3];
    float* out = (float*)d_out;

    char* base = (char*)d_ws;
    float*  Qt    = (float*)(base);                               // 8 MB
    float*  Pt    = (float*)(base + (8u << 20));                  // 8 MB
    ushort* Qpk   = (ushort*)(base + (16u << 20));                // 4 MB
    ushort* Ppk   = (ushort*)(base + (20u << 20));                // 4 MB
    char* x = base + (24u << 20);
    float*  qnorm = (float*)x;              x += 65536;           // 64 KB
    float*  Vmax  = (float*)x;              x += 262144;          // 256 KB
    float*  thr   = (float*)x;              x += 65536;           // 64 KB
    unsigned long long* best = (unsigned long long*)x; x += 131072; // 128 KB
    unsigned* bcnt = (unsigned*)x;          x += 4096;            // 512 u32
    unsigned* ocnt = (unsigned*)x;          x += 16;
    unsigned* cand = (unsigned*)x;          x += (size_t)512 * BCAP * 4; // 2 MB
    unsigned* ocand = (unsigned*)x;                               // 256 KB

    init_kernel<<<64, 256, 0, stream>>>(best, bcnt, ocnt);
    proj_kernel<<<dim3(64, 4, 2), 256, 0, stream>>>(Fq, Fp, Wm, bias,
                                                    Qt, Pt, Qpk, Ppk, qnorm);
    sim_max_kernel<<<dim3(32, 4, 4), 256, 0, stream>>>(Qpk, Ppk, Vmax);
    thresh_kernel<<<64, 256, 0, stream>>>(Vmax, qnorm, thr);
    sim_emit_kernel<<<dim3(32, 4, 4), 256, 0, stream>>>(Qpk, Ppk, thr,
                                                        cand, bcnt, ocand, ocnt);
    rescore_kernel<<<512, 256, 0, stream>>>(Qt, Pt, cand, bcnt, ocand, ocnt, best);
    gather_kernel<<<1024, 256, 0, stream>>>(Fp, best, out);
}

// Round 7
// 215.154 us; speedup vs baseline: 2.6262x; 1.1312x over previous
//
#include <hip/hip_runtime.h>

#define HW 4096
#define BCAP 1024u     // per-block candidate slots (expected ~64/block)
#define OCAP 65536u    // global overflow list (expected 0 used)

typedef short bf16x8 __attribute__((ext_vector_type(8)));
typedef float f32x16 __attribute__((ext_vector_type(16)));

__device__ __forceinline__ ushort f2bf_rne(float f) {
    unsigned u = __float_as_uint(f);
    return (ushort)((u + 0x7FFFu + ((u >> 16) & 1u)) >> 16);
}

// ---------------------------------------------------------------------------
// init: zero per-(b,n) best keys, per-block candidate counts, overflow count.
// ---------------------------------------------------------------------------
__global__ __launch_bounds__(256) void init_kernel(
    unsigned long long* __restrict__ best, unsigned* __restrict__ bcnt,
    unsigned* __restrict__ ocnt)
{
    int i = blockIdx.x * 256 + threadIdx.x;   // 16384
    best[i] = 0ull;
    if (i < 512) bcnt[i] = 0u;
    if (i == 0) ocnt[0] = 0u;
}

// ---------------------------------------------------------------------------
// W transpose: Wt[c][o] = W[o][c].  128 KB once.  Makes proj's per-r scalar
// W reads CONTIGUOUS (4 x s_load_dwordx8) instead of 32 loads at 1 KB stride
// (which thrashed the scalar cache's sets -> the R6 108 us miss storm).
// ---------------------------------------------------------------------------
__global__ __launch_bounds__(256) void transpose_w_kernel(
    const float* __restrict__ Wm, float* __restrict__ Wt)
{
    const int o = blockIdx.x;        // 128
    const int c = threadIdx.x;       // 256
    Wt[c * 128 + o] = Wm[o * 256 + c];
}

// ---------------------------------------------------------------------------
// Kernel 1: 1x1-conv projection.  Identical accumulation order to R6
// (bitwise-same outputs); only the W fetch path changed to the transposed
// contiguous layout.
// Outputs: Qt/Pt fp32 [b][n][128] (rescore), qnorm, and bf16 packs in
// 32x32x16-MFMA fragment order:
//   PK[b][t32][ks][lane][j] = X[c = ks*16 + (lane>>5)*8 + j][n = t32*32 + (lane&31)]
// ---------------------------------------------------------------------------
__global__ __launch_bounds__(256) void proj_kernel(
    const float* __restrict__ Fq, const float* __restrict__ Fp,
    const float* __restrict__ Wt, const float* __restrict__ bias,
    float* __restrict__ Qt, float* __restrict__ Pt,
    ushort* __restrict__ Qpk, ushort* __restrict__ Ppk,
    float* __restrict__ qnorm)
{
    __shared__ float Xs[64][64];
    __shared__ float sq[4][64];

    const int tid = threadIdx.x;
    const int z = blockIdx.z;
    const float* __restrict__ X = z ? Fp : Fq;
    const int b  = blockIdx.y;
    const int n0 = blockIdx.x * 64;
    const int n  = tid & 63;
    const int og = __builtin_amdgcn_readfirstlane(tid >> 6);

    float acc[32];
    #pragma unroll
    for (int j = 0; j < 32; ++j) acc[j] = 0.f;

    for (int cc = 0; cc < 4; ++cc) {
        #pragma unroll
        for (int i = 0; i < 16; ++i) {
            int idx = tid + i * 256;
            int r = idx >> 6, nn = idx & 63;
            Xs[r][nn] = X[(size_t)(b * 256 + cc * 64 + r) * HW + n0 + nn];
        }
        __syncthreads();
        for (int r = 0; r < 64; ++r) {
            float x = Xs[r][n];
            int c = cc * 64 + r;
            #pragma unroll
            for (int j = 0; j < 32; ++j)
                acc[j] += Wt[c * 128 + og * 32 + j] * x;   // contiguous scalar loads
        }
        __syncthreads();
    }

    #pragma unroll
    for (int j = 0; j < 32; ++j) acc[j] += bias[og * 32 + j];

    float ssq = 0.f;
    #pragma unroll
    for (int j = 0; j < 32; ++j) ssq += acc[j] * acc[j];
    sq[og][n] = ssq;
    __syncthreads();
    float tot = sq[0][n] + sq[1][n] + sq[2][n] + sq[3][n];
    if (z) {
        float s = 1.0f / sqrtf(tot);
        #pragma unroll
        for (int j = 0; j < 32; ++j) acc[j] *= s;
    } else if (og == 0) {
        qnorm[b * HW + n0 + n] = sqrtf(tot);
    }

    {
        float* __restrict__ T = z ? Pt : Qt;
        size_t tb = ((size_t)b * HW + n0 + n) * 128 + og * 32;
        #pragma unroll
        for (int j = 0; j < 32; j += 4)
            *(float4*)&T[tb + j] = make_float4(acc[j], acc[j+1], acc[j+2], acc[j+3]);
    }
    {
        ushort* __restrict__ PK = z ? Ppk : Qpk;
        const int na  = n0 + n;
        const int t32 = na >> 5;
        const int nl  = na & 31;
        #pragma unroll
        for (int g = 0; g < 4; ++g) {
            const int ks = og * 2 + (g >> 1);
            const int lt = nl + 32 * (g & 1);
            ushort u[8];
            #pragma unroll
            for (int k = 0; k < 8; ++k) u[k] = f2bf_rne(acc[g * 8 + k]);
            size_t pk = ((((size_t)b * 128 + t32) * 8 + ks) * 64 + lt) * 8;
            uint4 w;
            w.x = (unsigned)u[0] | ((unsigned)u[1] << 16);
            w.y = (unsigned)u[2] | ((unsigned)u[3] << 16);
            w.z = (unsigned)u[4] | ((unsigned)u[5] << 16);
            w.w = (unsigned)u[6] | ((unsigned)u[7] << 16);
            *(uint4*)&PK[pk] = w;
        }
    }
}

// ---------------------------------------------------------------------------
// PASS 1: MFMA sim max.  Grid (32,4,4): block = 128 n x 1024 m; wave owns a
// 32-row n-tile; 8 m-chunks of 128 through 32 KB LDS; 32x32x16 MFMA chained
// 8 deep over K=128.  D mapping: m = lane&31, n = (r&3)+8*(r>>2)+4*(lane>>5).
// ---------------------------------------------------------------------------
__global__ __launch_bounds__(256, 2) void sim_max_kernel(
    const ushort* __restrict__ Qpk, const ushort* __restrict__ Ppk,
    float* __restrict__ Vmax)
{
    __shared__ ushort Qs[16384];
    __shared__ ushort Bs[16384];

    const int tid  = threadIdx.x;
    const int lane = tid & 63;
    const int w    = tid >> 6;
    const int nb   = blockIdx.x;
    const int b    = blockIdx.y;
    const int ms   = blockIdx.z;

    {
        const uint4* src = (const uint4*)(Qpk + ((size_t)b * 128 + nb * 4) * 4096);
        uint4* dst = (uint4*)Qs;
        #pragma unroll
        for (int it = 0; it < 8; ++it) dst[it * 256 + tid] = src[it * 256 + tid];
    }

    float bestv[16];
    #pragma unroll
    for (int r = 0; r < 16; ++r) bestv[r] = -1e30f;

    for (int ch = 0; ch < 8; ++ch) {
        __syncthreads();
        {
            const uint4* src = (const uint4*)(Ppk +
                ((size_t)b * 128 + ms * 32 + ch * 4) * 4096);
            uint4* dst = (uint4*)Bs;
            #pragma unroll
            for (int it = 0; it < 8; ++it) dst[it * 256 + tid] = src[it * 256 + tid];
        }
        __syncthreads();

        for (int mtl = 0; mtl < 4; ++mtl) {
            f32x16 acc;
            #pragma unroll
            for (int r = 0; r < 16; ++r) acc[r] = 0.f;
            #pragma unroll
            for (int ks = 0; ks < 8; ++ks) {
                bf16x8 a  = *(const bf16x8*)&Qs[((w   * 8 + ks) * 64 + lane) * 8];
                bf16x8 bb = *(const bf16x8*)&Bs[((mtl * 8 + ks) * 64 + lane) * 8];
                acc = __builtin_amdgcn_mfma_f32_32x32x16_bf16(a, bb, acc, 0, 0, 0);
            }
            #pragma unroll
            for (int r = 0; r < 16; ++r)
                bestv[r] = fmaxf(bestv[r], acc[r]);
        }
    }

    #pragma unroll
    for (int r = 0; r < 16; ++r) {
        float v = bestv[r];
        #pragma unroll
        for (int d = 1; d < 32; d <<= 1)
            v = fmaxf(v, __shfl_xor(v, d, 64));
        if ((lane & 31) == 0) {
            int nl_ = (r & 3) + 8 * (r >> 2) + 4 * (lane >> 5);
            int na = nb * 128 + w * 32 + nl_;
            Vmax[((size_t)b * HW + na) * 4 + ms] = v;
        }
    }
}

// ---------------------------------------------------------------------------
// PASS 2: emit candidates with s >= thr[n].  SAME MFMA chain order as pass 1
// -> bitwise-identical s.  LDS counter + per-block candidate region (R6 fix:
// single global atomic counter was serializing ~32k device RMWs = 343 us).
// ---------------------------------------------------------------------------
__global__ __launch_bounds__(256, 2) void sim_emit_kernel(
    const ushort* __restrict__ Qpk, const ushort* __restrict__ Ppk,
    const float* __restrict__ thr,
    unsigned* __restrict__ cand, unsigned* __restrict__ bcnt,
    unsigned* __restrict__ ocand, unsigned* __restrict__ ocnt)
{
    __shared__ ushort Qs[16384];
    __shared__ ushort Bs[16384];
    __shared__ unsigned lds_cand[BCAP];
    __shared__ unsigned lds_cnt;

    const int tid  = threadIdx.x;
    const int lane = tid & 63;
    const int w    = tid >> 6;
    const int nb   = blockIdx.x;
    const int b    = blockIdx.y;
    const int ms   = blockIdx.z;
    const int blk  = nb + 32 * (b + 4 * ms);   // 512 regions

    if (tid == 0) lds_cnt = 0u;

    {
        const uint4* src = (const uint4*)(Qpk + ((size_t)b * 128 + nb * 4) * 4096);
        uint4* dst = (uint4*)Qs;
        #pragma unroll
        for (int it = 0; it < 8; ++it) dst[it * 256 + tid] = src[it * 256 + tid];
    }

    float thrreg[16];
    #pragma unroll
    for (int r = 0; r < 16; ++r) {
        int nl_ = (r & 3) + 8 * (r >> 2) + 4 * (lane >> 5);
        thrreg[r] = thr[b * HW + nb * 128 + w * 32 + nl_];
    }

    for (int ch = 0; ch < 8; ++ch) {
        __syncthreads();   // orders lds_cnt init + Qs stage + prior Bs reads
        {
            const uint4* src = (const uint4*)(Ppk +
                ((size_t)b * 128 + ms * 32 + ch * 4) * 4096);
            uint4* dst = (uint4*)Bs;
            #pragma unroll
            for (int it = 0; it < 8; ++it) dst[it * 256 + tid] = src[it * 256 + tid];
        }
        __syncthreads();

        for (int mtl = 0; mtl < 4; ++mtl) {
            f32x16 acc;
            #pragma unroll
            for (int r = 0; r < 16; ++r) acc[r] = 0.f;
            #pragma unroll
            for (int ks = 0; ks < 8; ++ks) {
                bf16x8 a  = *(const bf16x8*)&Qs[((w   * 8 + ks) * 64 + lane) * 8];
                bf16x8 bb = *(const bf16x8*)&Bs[((mtl * 8 + ks) * 64 + lane) * 8];
                acc = __builtin_amdgcn_mfma_f32_32x32x16_bf16(a, bb, acc, 0, 0, 0);
            }

            const int m = ms * 1024 + ch * 128 + mtl * 32 + (lane & 31);
            #pragma unroll
            for (int r = 0; r < 16; ++r) {
                if (acc[r] >= thrreg[r]) {
                    int nl_ = (r & 3) + 8 * (r >> 2) + 4 * (lane >> 5);
                    int na = nb * 128 + w * 32 + nl_;
                    unsigned enc = ((unsigned)b << 24) | ((unsigned)na << 12) | (unsigned)m;
                    unsigned pos = atomicAdd(&lds_cnt, 1u);   // LDS: per-CU, fast
                    if (pos < BCAP) {
                        lds_cand[pos] = enc;
                    } else {                                  // overflow fallback
                        unsigned op = atomicAdd(ocnt, 1u);
                        if (op < OCAP) ocand[op] = enc;
                    }
                }
            }
        }
    }

    __syncthreads();
    unsigned cnt = lds_cnt;
    if (cnt > BCAP) cnt = BCAP;
    for (unsigned i = tid; i < cnt; i += 256)
        cand[(size_t)blk * BCAP + i] = lds_cand[i];
    if (tid == 0) bcnt[blk] = cnt;
}

// ---------------------------------------------------------------------------
// threshold: thr[n] = max_s Vmax[n][s] - (0.016*||q_n|| + 1e-6)
// margin: |s_bf16 - s_fp32| < 0.00787*||q||  ->  2*delta < 0.016*||q||
// ---------------------------------------------------------------------------
__global__ __launch_bounds__(256) void thresh_kernel(
    const float* __restrict__ Vmax, const float* __restrict__ qnorm,
    float* __restrict__ thr)
{
    int i = blockIdx.x * 256 + threadIdx.x;   // 16384
    float g = -1e30f;
    #pragma unroll
    for (int s = 0; s < 4; ++s) g = fmaxf(g, Vmax[(size_t)i * 4 + s]);
    thr[i] = g - (0.016f * qnorm[i] + 1e-6f);
}

// ---------------------------------------------------------------------------
// exact fp32 rescore (sequential-c fma chain).  Block j consumes region j,
// then grid-strides overflow.  Packed u64 atomicMax, distinct addresses.
// ---------------------------------------------------------------------------
__device__ __forceinline__ void rescore_one(
    const float* __restrict__ Qt, const float* __restrict__ Pt,
    unsigned c, unsigned long long* __restrict__ best)
{
    int m = c & 0xFFF, n = (c >> 12) & 0xFFF, b = c >> 24;
    const float* __restrict__ q = Qt + ((size_t)b * HW + n) * 128;
    const float* __restrict__ p = Pt + ((size_t)b * HW + m) * 128;
    float acc = 0.f;
    for (int k = 0; k < 128; ++k) acc += q[k] * p[k];
    unsigned u = __float_as_uint(acc);
    unsigned kk = (u & 0x80000000u) ? ~u : (u | 0x80000000u);
    unsigned long long key = ((unsigned long long)kk << 32) | (unsigned)(4095 - m);
    atomicMax(&best[(size_t)b * HW + n], key);
}

__global__ __launch_bounds__(256) void rescore_kernel(
    const float* __restrict__ Qt, const float* __restrict__ Pt,
    const unsigned* __restrict__ cand, const unsigned* __restrict__ bcnt,
    const unsigned* __restrict__ ocand, const unsigned* __restrict__ ocnt,
    unsigned long long* __restrict__ best)
{
    const int blk = blockIdx.x;          // 512
    const int tid = threadIdx.x;
    unsigned cnt = bcnt[blk];
    for (unsigned i = tid; i < cnt; i += 256)
        rescore_one(Qt, Pt, cand[(size_t)blk * BCAP + i], best);

    unsigned total = ocnt[0];
    if (total > OCAP) total = OCAP;
    for (unsigned i = blk * 256 + tid; i < total; i += 512 * 256)
        rescore_one(Qt, Pt, ocand[i], best);
}

// ---------------------------------------------------------------------------
// gather: out[b][c][n] = Fp[b][c][m(n)]; stage each 16 KB Fp row in LDS.
// ---------------------------------------------------------------------------
__global__ __launch_bounds__(256) void gather_kernel(
    const float* __restrict__ Fp, const unsigned long long* __restrict__ best,
    float* __restrict__ out)
{
    __shared__ float row[4096];
    const int blk = blockIdx.x;      // 1024 = 4b x 256c
    const int c = blk & 255;
    const int b = blk >> 8;
    const int tid = threadIdx.x;

    const float* __restrict__ src = Fp + ((size_t)b * 256 + c) * HW;
    #pragma unroll
    for (int it = 0; it < 4; ++it) {
        int f = it * 256 + tid;
        *(float4*)&row[f * 4] = *(const float4*)&src[f * 4];
    }
    __syncthreads();

    float* __restrict__ dst = out + ((size_t)b * 256 + c) * HW;
    #pragma unroll
    for (int it = 0; it < 16; ++it) {
        int n = it * 256 + tid;
        int m = 4095 - (int)(best[(size_t)b * HW + n] & 0xFFFull);
        dst[n] = row[m];
    }
}

extern "C" void kernel_launch(void* const* d_in, const int* in_sizes, int n_in,
                              void* d_out, int out_size, void* d_ws, size_t ws_size,
                              hipStream_t stream) {
    const float* Fq   = (const float*)d_in[0];
    const float* Fp   = (const float*)d_in[1];
    const float* Wm   = (const float*)d_in[2];
    const float* bias = (const float*)d_in[3];
    float* out = (float*)d_out;

    char* base = (char*)d_ws;
    float*  Qt    = (float*)(base);                               // 8 MB
    float*  Pt    = (float*)(base + (8u << 20));                  // 8 MB
    ushort* Qpk   = (ushort*)(base + (16u << 20));                // 4 MB
    ushort* Ppk   = (ushort*)(base + (20u << 20));                // 4 MB
    char* x = base + (24u << 20);
    float*  qnorm = (float*)x;              x += 65536;           // 64 KB
    float*  Vmax  = (float*)x;              x += 262144;          // 256 KB
    float*  thr   = (float*)x;              x += 65536;           // 64 KB
    unsigned long long* best = (unsigned long long*)x; x += 131072; // 128 KB
    unsigned* bcnt = (unsigned*)x;          x += 4096;            // 512 u32
    unsigned* ocnt = (unsigned*)x;          x += 16;
    unsigned* cand = (unsigned*)x;          x += (size_t)512 * BCAP * 4; // 2 MB
    unsigned* ocand = (unsigned*)x;         x += OCAP * 4;        // 256 KB
    float*  Wtg   = (float*)x;                                    // 128 KB

    init_kernel<<<64, 256, 0, stream>>>(best, bcnt, ocnt);
    transpose_w_kernel<<<128, 256, 0, stream>>>(Wm, Wtg);
    proj_kernel<<<dim3(64, 4, 2), 256, 0, stream>>>(Fq, Fp, Wtg, bias,
                                                    Qt, Pt, Qpk, Ppk, qnorm);
    sim_max_kernel<<<dim3(32, 4, 4), 256, 0, stream>>>(Qpk, Ppk, Vmax);
    thresh_kernel<<<64, 256, 0, stream>>>(Vmax, qnorm, thr);
    sim_emit_kernel<<<dim3(32, 4, 4), 256, 0, stream>>>(Qpk, Ppk, thr,
                                                        cand, bcnt, ocand, ocnt);
    rescore_kernel<<<512, 256, 0, stream>>>(Qt, Pt, cand, bcnt, ocand, ocnt, best);
    gather_kernel<<<1024, 256, 0, stream>>>(Fp, best, out);
}

// Round 8
// 176.011 us; speedup vs baseline: 3.2102x; 1.2224x over previous
//
#include <hip/hip_runtime.h>

#define HW 4096
#define BCAP 1024u     // per-block candidate slots (expected ~64/block)
#define OCAP 65536u    // global overflow list (expected 0 used)

typedef short bf16x8 __attribute__((ext_vector_type(8)));
typedef float f32x16 __attribute__((ext_vector_type(16)));

__device__ __forceinline__ ushort f2bf_rne(float f) {
    unsigned u = __float_as_uint(f);
    return (ushort)((u + 0x7FFFu + ((u >> 16) & 1u)) >> 16);
}

// ---------------------------------------------------------------------------
// init: zero per-(b,n) best keys, per-block candidate counts, overflow count.
// ---------------------------------------------------------------------------
__global__ __launch_bounds__(256) void init_kernel(
    unsigned long long* __restrict__ best, unsigned* __restrict__ bcnt,
    unsigned* __restrict__ ocnt)
{
    int i = blockIdx.x * 256 + threadIdx.x;   // 16384
    best[i] = 0ull;
    if (i < 512) bcnt[i] = 0u;
    if (i == 0) ocnt[0] = 0u;
}

// ---------------------------------------------------------------------------
// W transpose: Wt[c][o] = W[o][c].  128 KB once; gives proj contiguous
// per-c rows for LDS staging.
// ---------------------------------------------------------------------------
__global__ __launch_bounds__(256) void transpose_w_kernel(
    const float* __restrict__ Wm, float* __restrict__ Wt)
{
    const int o = blockIdx.x;        // 128
    const int c = threadIdx.x;       // 256
    Wt[c * 128 + o] = Wm[o * 256 + c];
}

// ---------------------------------------------------------------------------
// Kernel 1: 1x1-conv projection as an LDS-tiled vector GEMM.
// R7 forensics: W via scalar loads kept SMEM in the inner loop; SMEM shares
// lgkmcnt with ds_read and returns out-of-order -> every r forced
// lgkmcnt(0) drain (~200 cyc) => 74 us at 20% VALUBusy.  Now W lives in LDS
// (vector-staged); all inner-loop waits are in-order ds reads.
// Thread (og,ng) owns an 8o x 4n register tile; accumulation stays
// sequential-c per output => Qt/Pt/packs bitwise-identical to R6/R7
// (norm partial-sum order differs by ~1 ulp in a positive scale; harmless).
// Outputs: Qt/Pt fp32 [b][n][128], qnorm, bf16 packs in 32x32x16 fragment
// order: PK[b][t32][ks][lt][j] = proj[c=ks*16+(lt>>5)*8+j][n=t32*32+(lt&31)].
// ---------------------------------------------------------------------------
__global__ __launch_bounds__(256) void proj_kernel(
    const float* __restrict__ Fq, const float* __restrict__ Fp,
    const float* __restrict__ Wt, const float* __restrict__ bias,
    float* __restrict__ Qt, float* __restrict__ Pt,
    ushort* __restrict__ Qpk, ushort* __restrict__ Ppk,
    float* __restrict__ qnorm)
{
    __shared__ float Ws[64][128];    // 32 KB: c-chunk x o
    __shared__ float Xs[64][64];     // 16 KB: c-chunk x n
    __shared__ float psum[16][68];   // 4.25 KB padded norm partials

    const int tid = threadIdx.x;
    const int z  = blockIdx.z;                 // 0: q, 1: p
    const float* __restrict__ X = z ? Fp : Fq;
    const int b  = blockIdx.y;
    const int n0 = blockIdx.x * 64;
    const int og = tid >> 4;                   // 0..15 -> o = og*8 .. +8
    const int ng = tid & 15;                   // 0..15 -> n = n0+ng*4 .. +4

    float acc[4][8];                           // [n][o]
    #pragma unroll
    for (int i = 0; i < 4; ++i)
        #pragma unroll
        for (int j = 0; j < 8; ++j) acc[i][j] = 0.f;

    for (int cc = 0; cc < 4; ++cc) {
        __syncthreads();                       // protect prior chunk's reads
        // stage W chunk: rows c = cc*64..+63, 128 o each (contiguous f4s)
        {
            const float4* src = (const float4*)(Wt + (size_t)cc * 64 * 128);
            float4* dst = (float4*)Ws;
            #pragma unroll
            for (int it = 0; it < 8; ++it) dst[it * 256 + tid] = src[it * 256 + tid];
        }
        // stage X chunk: rows c = cc*64..+63, cols n0..n0+63
        #pragma unroll
        for (int it = 0; it < 4; ++it) {
            int f = it * 256 + tid;
            int r = f >> 4, n4 = f & 15;
            *(float4*)&Xs[r][n4 * 4] =
                *(const float4*)&X[(size_t)(b * 256 + cc * 64 + r) * HW + n0 + n4 * 4];
        }
        __syncthreads();

        for (int r = 0; r < 64; ++r) {
            float4 w0 = *(const float4*)&Ws[r][og * 8];
            float4 w1 = *(const float4*)&Ws[r][og * 8 + 4];
            float4 xv = *(const float4*)&Xs[r][ng * 4];
            float wa[8] = {w0.x, w0.y, w0.z, w0.w, w1.x, w1.y, w1.z, w1.w};
            float xa[4] = {xv.x, xv.y, xv.z, xv.w};
            #pragma unroll
            for (int i = 0; i < 4; ++i)
                #pragma unroll
                for (int j = 0; j < 8; ++j)
                    acc[i][j] += wa[j] * xa[i];
        }
    }

    // bias
    {
        float4 b0 = *(const float4*)&bias[og * 8];
        float4 b1 = *(const float4*)&bias[og * 8 + 4];
        float ba[8] = {b0.x, b0.y, b0.z, b0.w, b1.x, b1.y, b1.z, b1.w};
        #pragma unroll
        for (int i = 0; i < 4; ++i)
            #pragma unroll
            for (int j = 0; j < 8; ++j) acc[i][j] += ba[j];
    }

    // channel-sumsq partials -> full 128-channel sums per n
    #pragma unroll
    for (int i = 0; i < 4; ++i) {
        float s = 0.f;
        #pragma unroll
        for (int j = 0; j < 8; ++j) s += acc[i][j] * acc[i][j];
        psum[og][ng * 4 + i] = s;
    }
    __syncthreads();
    float tot[4];
    #pragma unroll
    for (int i = 0; i < 4; ++i) {
        float s = 0.f;
        #pragma unroll
        for (int g = 0; g < 16; ++g) s += psum[g][ng * 4 + i];
        tot[i] = s;
    }

    if (z) {   // normalize p over its 128 channels
        #pragma unroll
        for (int i = 0; i < 4; ++i) {
            float s = 1.0f / sqrtf(tot[i]);
            #pragma unroll
            for (int j = 0; j < 8; ++j) acc[i][j] *= s;
        }
    } else if (og == 0) {
        #pragma unroll
        for (int i = 0; i < 4; ++i)
            qnorm[b * HW + n0 + ng * 4 + i] = sqrtf(tot[i]);
    }

    // fp32 transposed output for rescore
    {
        float* __restrict__ T = z ? Pt : Qt;
        #pragma unroll
        for (int i = 0; i < 4; ++i) {
            size_t tb = ((size_t)b * HW + n0 + ng * 4 + i) * 128 + og * 8;
            *(float4*)&T[tb]     = make_float4(acc[i][0], acc[i][1], acc[i][2], acc[i][3]);
            *(float4*)&T[tb + 4] = make_float4(acc[i][4], acc[i][5], acc[i][6], acc[i][7]);
        }
    }
    // bf16 pack: thread's 8 channels are exactly one fragment j-group:
    // ks = og>>1, lt = (n&31) + 32*(og&1), t32 = n>>5
    {
        ushort* __restrict__ PK = z ? Ppk : Qpk;
        const int ks = og >> 1;
        #pragma unroll
        for (int i = 0; i < 4; ++i) {
            const int na  = n0 + ng * 4 + i;
            const int t32 = na >> 5;
            const int lt  = (na & 31) + 32 * (og & 1);
            ushort u[8];
            #pragma unroll
            for (int k = 0; k < 8; ++k) u[k] = f2bf_rne(acc[i][k]);
            size_t pk = ((((size_t)b * 128 + t32) * 8 + ks) * 64 + lt) * 8;
            uint4 w;
            w.x = (unsigned)u[0] | ((unsigned)u[1] << 16);
            w.y = (unsigned)u[2] | ((unsigned)u[3] << 16);
            w.z = (unsigned)u[4] | ((unsigned)u[5] << 16);
            w.w = (unsigned)u[6] | ((unsigned)u[7] << 16);
            *(uint4*)&PK[pk] = w;
        }
    }
}

// ---------------------------------------------------------------------------
// PASS 1: MFMA sim max.  Grid (32,4,4): block = 128 n x 1024 m; wave owns a
// 32-row n-tile; 8 m-chunks of 128 through 32 KB LDS; 32x32x16 MFMA chained
// 8 deep over K=128.  D mapping: m = lane&31, n = (r&3)+8*(r>>2)+4*(lane>>5).
// ---------------------------------------------------------------------------
__global__ __launch_bounds__(256, 2) void sim_max_kernel(
    const ushort* __restrict__ Qpk, const ushort* __restrict__ Ppk,
    float* __restrict__ Vmax)
{
    __shared__ ushort Qs[16384];
    __shared__ ushort Bs[16384];

    const int tid  = threadIdx.x;
    const int lane = tid & 63;
    const int w    = tid >> 6;
    const int nb   = blockIdx.x;
    const int b    = blockIdx.y;
    const int ms   = blockIdx.z;

    {
        const uint4* src = (const uint4*)(Qpk + ((size_t)b * 128 + nb * 4) * 4096);
        uint4* dst = (uint4*)Qs;
        #pragma unroll
        for (int it = 0; it < 8; ++it) dst[it * 256 + tid] = src[it * 256 + tid];
    }

    float bestv[16];
    #pragma unroll
    for (int r = 0; r < 16; ++r) bestv[r] = -1e30f;

    for (int ch = 0; ch < 8; ++ch) {
        __syncthreads();
        {
            const uint4* src = (const uint4*)(Ppk +
                ((size_t)b * 128 + ms * 32 + ch * 4) * 4096);
            uint4* dst = (uint4*)Bs;
            #pragma unroll
            for (int it = 0; it < 8; ++it) dst[it * 256 + tid] = src[it * 256 + tid];
        }
        __syncthreads();

        for (int mtl = 0; mtl < 4; ++mtl) {
            f32x16 acc;
            #pragma unroll
            for (int r = 0; r < 16; ++r) acc[r] = 0.f;
            #pragma unroll
            for (int ks = 0; ks < 8; ++ks) {
                bf16x8 a  = *(const bf16x8*)&Qs[((w   * 8 + ks) * 64 + lane) * 8];
                bf16x8 bb = *(const bf16x8*)&Bs[((mtl * 8 + ks) * 64 + lane) * 8];
                acc = __builtin_amdgcn_mfma_f32_32x32x16_bf16(a, bb, acc, 0, 0, 0);
            }
            #pragma unroll
            for (int r = 0; r < 16; ++r)
                bestv[r] = fmaxf(bestv[r], acc[r]);
        }
    }

    #pragma unroll
    for (int r = 0; r < 16; ++r) {
        float v = bestv[r];
        #pragma unroll
        for (int d = 1; d < 32; d <<= 1)
            v = fmaxf(v, __shfl_xor(v, d, 64));
        if ((lane & 31) == 0) {
            int nl_ = (r & 3) + 8 * (r >> 2) + 4 * (lane >> 5);
            int na = nb * 128 + w * 32 + nl_;
            Vmax[((size_t)b * HW + na) * 4 + ms] = v;
        }
    }
}

// ---------------------------------------------------------------------------
// PASS 2: emit candidates with s >= thr[n].  SAME MFMA chain order as pass 1
// -> bitwise-identical s.  LDS counter + per-block candidate region (R6 fix:
// single global atomic counter was serializing ~32k device RMWs = 343 us).
// ---------------------------------------------------------------------------
__global__ __launch_bounds__(256, 2) void sim_emit_kernel(
    const ushort* __restrict__ Qpk, const ushort* __restrict__ Ppk,
    const float* __restrict__ thr,
    unsigned* __restrict__ cand, unsigned* __restrict__ bcnt,
    unsigned* __restrict__ ocand, unsigned* __restrict__ ocnt)
{
    __shared__ ushort Qs[16384];
    __shared__ ushort Bs[16384];
    __shared__ unsigned lds_cand[BCAP];
    __shared__ unsigned lds_cnt;

    const int tid  = threadIdx.x;
    const int lane = tid & 63;
    const int w    = tid >> 6;
    const int nb   = blockIdx.x;
    const int b    = blockIdx.y;
    const int ms   = blockIdx.z;
    const int blk  = nb + 32 * (b + 4 * ms);   // 512 regions

    if (tid == 0) lds_cnt = 0u;

    {
        const uint4* src = (const uint4*)(Qpk + ((size_t)b * 128 + nb * 4) * 4096);
        uint4* dst = (uint4*)Qs;
        #pragma unroll
        for (int it = 0; it < 8; ++it) dst[it * 256 + tid] = src[it * 256 + tid];
    }

    float thrreg[16];
    #pragma unroll
    for (int r = 0; r < 16; ++r) {
        int nl_ = (r & 3) + 8 * (r >> 2) + 4 * (lane >> 5);
        thrreg[r] = thr[b * HW + nb * 128 + w * 32 + nl_];
    }

    for (int ch = 0; ch < 8; ++ch) {
        __syncthreads();   // orders lds_cnt init + Qs stage + prior Bs reads
        {
            const uint4* src = (const uint4*)(Ppk +
                ((size_t)b * 128 + ms * 32 + ch * 4) * 4096);
            uint4* dst = (uint4*)Bs;
            #pragma unroll
            for (int it = 0; it < 8; ++it) dst[it * 256 + tid] = src[it * 256 + tid];
        }
        __syncthreads();

        for (int mtl = 0; mtl < 4; ++mtl) {
            f32x16 acc;
            #pragma unroll
            for (int r = 0; r < 16; ++r) acc[r] = 0.f;
            #pragma unroll
            for (int ks = 0; ks < 8; ++ks) {
                bf16x8 a  = *(const bf16x8*)&Qs[((w   * 8 + ks) * 64 + lane) * 8];
                bf16x8 bb = *(const bf16x8*)&Bs[((mtl * 8 + ks) * 64 + lane) * 8];
                acc = __builtin_amdgcn_mfma_f32_32x32x16_bf16(a, bb, acc, 0, 0, 0);
            }

            const int m = ms * 1024 + ch * 128 + mtl * 32 + (lane & 31);
            #pragma unroll
            for (int r = 0; r < 16; ++r) {
                if (acc[r] >= thrreg[r]) {
                    int nl_ = (r & 3) + 8 * (r >> 2) + 4 * (lane >> 5);
                    int na = nb * 128 + w * 32 + nl_;
                    unsigned enc = ((unsigned)b << 24) | ((unsigned)na << 12) | (unsigned)m;
                    unsigned pos = atomicAdd(&lds_cnt, 1u);   // LDS: per-CU, fast
                    if (pos < BCAP) {
                        lds_cand[pos] = enc;
                    } else {                                  // overflow fallback
                        unsigned op = atomicAdd(ocnt, 1u);
                        if (op < OCAP) ocand[op] = enc;
                    }
                }
            }
        }
    }

    __syncthreads();
    unsigned cnt = lds_cnt;
    if (cnt > BCAP) cnt = BCAP;
    for (unsigned i = tid; i < cnt; i += 256)
        cand[(size_t)blk * BCAP + i] = lds_cand[i];
    if (tid == 0) bcnt[blk] = cnt;
}

// ---------------------------------------------------------------------------
// threshold: thr[n] = max_s Vmax[n][s] - (0.016*||q_n|| + 1e-6)
// margin: |s_bf16 - s_fp32| < 0.00787*||q||  ->  2*delta < 0.016*||q||
// ---------------------------------------------------------------------------
__global__ __launch_bounds__(256) void thresh_kernel(
    const float* __restrict__ Vmax, const float* __restrict__ qnorm,
    float* __restrict__ thr)
{
    int i = blockIdx.x * 256 + threadIdx.x;   // 16384
    float g = -1e30f;
    #pragma unroll
    for (int s = 0; s < 4; ++s) g = fmaxf(g, Vmax[(size_t)i * 4 + s]);
    thr[i] = g - (0.016f * qnorm[i] + 1e-6f);
}

// ---------------------------------------------------------------------------
// exact fp32 rescore (sequential-c fma chain).  Block j consumes region j,
// then grid-strides overflow.  Packed u64 atomicMax, distinct addresses.
// ---------------------------------------------------------------------------
__device__ __forceinline__ void rescore_one(
    const float* __restrict__ Qt, const float* __restrict__ Pt,
    unsigned c, unsigned long long* __restrict__ best)
{
    int m = c & 0xFFF, n = (c >> 12) & 0xFFF, b = c >> 24;
    const float* __restrict__ q = Qt + ((size_t)b * HW + n) * 128;
    const float* __restrict__ p = Pt + ((size_t)b * HW + m) * 128;
    float acc = 0.f;
    for (int k = 0; k < 128; ++k) acc += q[k] * p[k];
    unsigned u = __float_as_uint(acc);
    unsigned kk = (u & 0x80000000u) ? ~u : (u | 0x80000000u);
    unsigned long long key = ((unsigned long long)kk << 32) | (unsigned)(4095 - m);
    atomicMax(&best[(size_t)b * HW + n], key);
}

__global__ __launch_bounds__(256) void rescore_kernel(
    const float* __restrict__ Qt, const float* __restrict__ Pt,
    const unsigned* __restrict__ cand, const unsigned* __restrict__ bcnt,
    const unsigned* __restrict__ ocand, const unsigned* __restrict__ ocnt,
    unsigned long long* __restrict__ best)
{
    const int blk = blockIdx.x;          // 512
    const int tid = threadIdx.x;
    unsigned cnt = bcnt[blk];
    for (unsigned i = tid; i < cnt; i += 256)
        rescore_one(Qt, Pt, cand[(size_t)blk * BCAP + i], best);

    unsigned total = ocnt[0];
    if (total > OCAP) total = OCAP;
    for (unsigned i = blk * 256 + tid; i < total; i += 512 * 256)
        rescore_one(Qt, Pt, ocand[i], best);
}

// ---------------------------------------------------------------------------
// gather: out[b][c][n] = Fp[b][c][m(n)]; stage each 16 KB Fp row in LDS.
// ---------------------------------------------------------------------------
__global__ __launch_bounds__(256) void gather_kernel(
    const float* __restrict__ Fp, const unsigned long long* __restrict__ best,
    float* __restrict__ out)
{
    __shared__ float row[4096];
    const int blk = blockIdx.x;      // 1024 = 4b x 256c
    const int c = blk & 255;
    const int b = blk >> 8;
    const int tid = threadIdx.x;

    const float* __restrict__ src = Fp + ((size_t)b * 256 + c) * HW;
    #pragma unroll
    for (int it = 0; it < 4; ++it) {
        int f = it * 256 + tid;
        *(float4*)&row[f * 4] = *(const float4*)&src[f * 4];
    }
    __syncthreads();

    float* __restrict__ dst = out + ((size_t)b * 256 + c) * HW;
    #pragma unroll
    for (int it = 0; it < 16; ++it) {
        int n = it * 256 + tid;
        int m = 4095 - (int)(best[(size_t)b * HW + n] & 0xFFFull);
        dst[n] = row[m];
    }
}

extern "C" void kernel_launch(void* const* d_in, const int* in_sizes, int n_in,
                              void* d_out, int out_size, void* d_ws, size_t ws_size,
                              hipStream_t stream) {
    const float* Fq   = (const float*)d_in[0];
    const float* Fp   = (const float*)d_in[1];
    const float* Wm   = (const float*)d_in[2];
    const float* bias = (const float*)d_in[3];
    float* out = (float*)d_out;

    char* base = (char*)d_ws;
    float*  Qt    = (float*)(base);                               // 8 MB
    float*  Pt    = (float*)(base + (8u << 20));                  // 8 MB
    ushort* Qpk   = (ushort*)(base + (16u << 20));                // 4 MB
    ushort* Ppk   = (ushort*)(base + (20u << 20));                // 4 MB
    char* x = base + (24u << 20);
    float*  qnorm = (float*)x;              x += 65536;           // 64 KB
    float*  Vmax  = (float*)x;              x += 262144;          // 256 KB
    float*  thr   = (float*)x;              x += 65536;           // 64 KB
    unsigned long long* best = (unsigned long long*)x; x += 131072; // 128 KB
    unsigned* bcnt = (unsigned*)x;          x += 4096;            // 512 u32
    unsigned* ocnt = (unsigned*)x;          x += 16;
    unsigned* cand = (unsigned*)x;          x += (size_t)512 * BCAP * 4; // 2 MB
    unsigned* ocand = (unsigned*)x;         x += OCAP * 4;        // 256 KB
    float*  Wtg   = (float*)x;                                    // 128 KB

    init_kernel<<<64, 256, 0, stream>>>(best, bcnt, ocnt);
    transpose_w_kernel<<<128, 256, 0, stream>>>(Wm, Wtg);
    proj_kernel<<<dim3(64, 4, 2), 256, 0, stream>>>(Fq, Fp, Wtg, bias,
                                                    Qt, Pt, Qpk, Ppk, qnorm);
    sim_max_kernel<<<dim3(32, 4, 4), 256, 0, stream>>>(Qpk, Ppk, Vmax);
    thresh_kernel<<<64, 256, 0, stream>>>(Vmax, qnorm, thr);
    sim_emit_kernel<<<dim3(32, 4, 4), 256, 0, stream>>>(Qpk, Ppk, thr,
                                                        cand, bcnt, ocand, ocnt);
    rescore_kernel<<<512, 256, 0, stream>>>(Qt, Pt, cand, bcnt, ocand, ocnt, best);
    gather_kernel<<<1024, 256, 0, stream>>>(Fp, best, out);
}